// Round 13
// baseline (721.382 us; speedup 1.0000x reference)
//
#include <hip/hip_runtime.h>
#include <math.h>

#define TT 32
#define MAXREC 8
#define NBLK 256
#define NTHR 512

// workspace byte offsets
#define OFF_ZBUF   0u          // 128*128 f32 = 65536 (exact z rows)
#define OFF_ZBUFB  65536u      // 128*128 bf16 = 32768 (z rows for MFMA)
#define OFF_KEYS   98304u      // 128 servers * 128 rows * 8B (tag-embedded)
#define OFF_ZDONE  229376u     // 128 * 16B: lo u64 {lo32=tag, hi32=z2}, hi u64 = finals overlay
#define OFF_ESQ    231424u     // 8192 f32 exact |e|^2
#define OFF_RST    264192u     // 128*4 f32
#define OFF_OUTHB  266240u     // 4096*128 bf16 = 1048576
#define OFF_WB     1314816u    // 2 MB: vqeB (main) then dWb (k_dec)

#define SENT 0x7FFFFFFFu
#define IDXM 0x1FFFu
#define LOGN 33554432u        // 128*32*8192
#define TWO_PI_F 6.283185307179586f

typedef float f32x4 __attribute__((ext_vector_type(4)));
typedef short bf16x8 __attribute__((ext_vector_type(8)));
typedef unsigned long long u64;

__device__ __forceinline__ float wredsum(float v) {
#pragma unroll
  for (int m = 32; m > 0; m >>= 1) v += __shfl_xor(v, m);
  return v;
}
__device__ __forceinline__ u64 shflx64(u64 v, int m) {
  int lo = __shfl_xor((int)(unsigned)(v & 0xffffffffull), m);
  int hi = __shfl_xor((int)(unsigned)(v >> 32), m);
  return ((u64)(unsigned)hi << 32) | (unsigned)lo;
}
// monotone float->u32 + 13-bit idx: u64-min == (min dist, then min idx)
__device__ __forceinline__ u64 packkey(float d, unsigned c) {
  unsigned u = __float_as_uint(d);
  u = (u & 0x80000000u) ? ~u : (u | 0x80000000u);
  return ((u64)u << 32) | c;
}
__device__ __forceinline__ float unpackd2(u64 key) {
  unsigned hi = (unsigned)(key >> 32);
  unsigned orig = (hi & 0x80000000u) ? (hi & 0x7fffffffu) : ~hi;
  return __uint_as_float(orig);
}
__device__ __forceinline__ unsigned short f2bf(float f) {
  unsigned u = __float_as_uint(f);
  unsigned r = (u >> 16) & 1u;
  u += 0x7fffu + r;
  return (unsigned short)(u >> 16);
}

// ---- coherent (cross-XCD, L2-bypass) accesses ----
__device__ __forceinline__ u64 ld_coh64(const u64* p) {
  u64 v;
  asm volatile("global_load_dwordx2 %0, %1, off sc0 sc1\n\ts_waitcnt vmcnt(0)"
               : "=&v"(v) : "v"(p) : "memory");
  return v;
}
__device__ __forceinline__ void st_coh_f32(float* p, float v) {
  asm volatile("global_store_dword %0, %1, off sc0 sc1" :: "v"(p), "v"(v) : "memory");
}
__device__ __forceinline__ void st_coh32(unsigned* p, unsigned v) {
  asm volatile("global_store_dword %0, %1, off sc0 sc1" :: "v"(p), "v"(v) : "memory");
}
__device__ __forceinline__ void st_coh64(u64* p, u64 v) {
  asm volatile("global_store_dwordx2 %0, %1, off sc0 sc1" :: "v"(p), "v"(v) : "memory");
}
__device__ __forceinline__ void drain_vm() {
  asm volatile("s_waitcnt vmcnt(0)" ::: "memory");
}
// 4 coherent 16B loads + wait (single round trip); byte offsets from base
__device__ __forceinline__ void ld4w(const float* base,
    unsigned o0, unsigned o1, unsigned o2, unsigned o3,
    f32x4& a0, f32x4& a1, f32x4& a2, f32x4& a3) {
  asm volatile(
      "global_load_dwordx4 %0, %4, %8 sc0 sc1\n\t"
      "global_load_dwordx4 %1, %5, %8 sc0 sc1\n\t"
      "global_load_dwordx4 %2, %6, %8 sc0 sc1\n\t"
      "global_load_dwordx4 %3, %7, %8 sc0 sc1\n\t"
      "s_waitcnt vmcnt(0)"
      : "=&v"(a0), "=&v"(a1), "=&v"(a2), "=&v"(a3)
      : "v"(o0), "v"(o1), "v"(o2), "v"(o3), "s"(base)
      : "memory");
}
// 8 coherent 16B loads + single wait
__device__ __forceinline__ void ld8w(const float* base,
    unsigned o0, unsigned o1, unsigned o2, unsigned o3,
    unsigned o4, unsigned o5, unsigned o6, unsigned o7,
    f32x4& a0, f32x4& a1, f32x4& a2, f32x4& a3,
    f32x4& a4, f32x4& a5, f32x4& a6, f32x4& a7) {
  asm volatile(
      "global_load_dwordx4 %0, %8, %16 sc0 sc1\n\t"
      "global_load_dwordx4 %1, %9, %16 sc0 sc1\n\t"
      "global_load_dwordx4 %2, %10, %16 sc0 sc1\n\t"
      "global_load_dwordx4 %3, %11, %16 sc0 sc1\n\t"
      "global_load_dwordx4 %4, %12, %16 sc0 sc1\n\t"
      "global_load_dwordx4 %5, %13, %16 sc0 sc1\n\t"
      "global_load_dwordx4 %6, %14, %16 sc0 sc1\n\t"
      "global_load_dwordx4 %7, %15, %16 sc0 sc1\n\t"
      "s_waitcnt vmcnt(0)"
      : "=&v"(a0), "=&v"(a1), "=&v"(a2), "=&v"(a3),
        "=&v"(a4), "=&v"(a5), "=&v"(a6), "=&v"(a7)
      : "v"(o0), "v"(o1), "v"(o2), "v"(o3),
        "v"(o4), "v"(o5), "v"(o6), "v"(o7),
        "s"(base)
      : "memory");
}

__global__ __launch_bounds__(512) void sacrsn_init(char* __restrict__ ws) {
  u64* zd = (u64*)(ws + OFF_ZDONE);
  if (threadIdx.x < 256) zd[threadIdx.x] = 0ull;  // tags + finals overlay
}

// vq_emb f32 -> bf16 (WB) + exact esq
__global__ __launch_bounds__(256) void k_prepv(const float* __restrict__ vqe,
                                               char* __restrict__ ws) {
  unsigned short* vqeB = (unsigned short*)(ws + OFF_WB);
  float* esqG = (float*)(ws + OFF_ESQ);
  const int i = (blockIdx.x * 256 + threadIdx.x) * 4;
  float4 v = *(const float4*)(vqe + i);
  ushort4 o;
  o.x = f2bf(v.x); o.y = f2bf(v.y); o.z = f2bf(v.z); o.w = f2bf(v.w);
  *(ushort4*)(vqeB + i) = o;
  if (blockIdx.x < 32) {
    const int c = blockIdx.x * 256 + threadIdx.x;
    const float4* e = (const float4*)(vqe + ((size_t)c << 7));
    float s = 0.f;
#pragma unroll 8
    for (int k4 = 0; k4 < 32; ++k4) {
      float4 q = e[k4];
      s = fmaf(q.x, q.x, fmaf(q.y, q.y, fmaf(q.z, q.z, fmaf(q.w, q.w, s))));
    }
    esqG[c] = s;
  }
}

// dec_W f32 -> bf16 (WB), runs AFTER main
__global__ __launch_bounds__(256) void k_prepd(const float* __restrict__ dW,
                                               char* __restrict__ ws) {
  unsigned short* dWb = (unsigned short*)(ws + OFF_WB);
  const int i = (blockIdx.x * 256 + threadIdx.x) * 4;
  float4 v = *(const float4*)(dW + i);
  ushort4 o;
  o.x = f2bf(v.x); o.y = f2bf(v.y); o.z = f2bf(v.z); o.w = f2bf(v.w);
  *(ushort4*)(dWb + i) = o;
}

__global__ __launch_bounds__(NTHR) void sacrsn_main(
    const int* __restrict__ x_seq, const float* __restrict__ enc,
    const float* __restrict__ vqe,
    const float* __restrict__ nrg, const float* __restrict__ nrb,
    const float* __restrict__ nig, const float* __restrict__ nib,
    const float* __restrict__ qWr, const float* __restrict__ qbr,
    const float* __restrict__ qWi, const float* __restrict__ qbi,
    const float* __restrict__ gtw, const float* __restrict__ gtb,
    const float* __restrict__ aW, const float* __restrict__ ab,
    const float* __restrict__ hbp, const float* __restrict__ igp,
    float* __restrict__ dout, char* __restrict__ ws)
{
  float* zbuf = (float*)(ws + OFF_ZBUF);
  unsigned* zbufB32 = (unsigned*)(ws + OFF_ZBUFB);
  u64*   keys = (u64*)(ws + OFF_KEYS);
  u64*   zdone64 = (u64*)(ws + OFF_ZDONE);       // slot r at [r*2]
  u64*   finalA = (u64*)(ws + OFF_ZDONE + 8u);   // slot r at [r*2] (upper half of 16B slot)
  const float* esqG = (const float*)(ws + OFF_ESQ);
  const unsigned short* vqeB = (const unsigned short*)(ws + OFF_WB);
  unsigned short* outhB = (unsigned short*)(ws + OFF_OUTHB);
  float* rst  = (float*)(ws + OFF_RST);

  const int tid = threadIdx.x;
  const int wv = tid >> 6, ln = tid & 63;
  const int blk = blockIdx.x;
  const bool owner = (blk < 128);

  // ---- LDS ----
  __shared__ float memLr[32 * 65];
  __shared__ float memLi[32 * 65];
  __shared__ float gwrowL[128], pangL[64], zfmL[128], zqL[128];
  __shared__ float qkL[6][64], simL[32], attnL[32], mrL[64], miL[64];
  __shared__ unsigned idxL[128] __attribute__((aligned(16)));
  __shared__ u64 key128L[128], kred[128];
  __shared__ float arbWL[3 * 128];
  __shared__ float scalL[8], entpL[2], vqpL[2], wsumL[2], z2pL[2];
  __shared__ float accL[4], totL[4];
  __shared__ float dmeanS;
  __shared__ u64 actM[2], actN[2];
  // server-side
  __shared__ float z2L[128], sz2L[128];
  __shared__ u64 rowminU[128];
  __shared__ unsigned candL[8192];
  __shared__ unsigned candCount;

  const float alpha = 1.0f / (1.0f + expf(-igp[0]));
  const float onema = 1.0f - alpha;
  const float hbias = log1pf(expf(hbp[0]));
  const float gtb0 = gtb[0];

  if (!owner) {
    // ================= VQ server: blocks 128..255, 64 codes, MFMA + exact rescue =================
    const int s = blk - 128;
    const int w = tid >> 6, l = tid & 63;      // wave w owns rows w*16..w*16+15
    const int ar = l & 15, kg = l >> 4;
    const int rowbase = w * 16;
    if (tid < 128) rowminU[tid] = ~0ull;
    if (tid == 0) candCount = 0u;
    __syncthreads();
    unsigned k = 0;
    while (true) {
      // ---- per-wave fused tag+z2 poll of own 16 rows (no block syncs per round) ----
      u64 tv;
      bool done;
      {
        const u64* tp = &zdone64[(size_t)(rowbase + ar) * 2];
        bool sent;
        while (true) {
          tv = ld_coh64(tp);
          unsigned lo = (unsigned)tv;
          sent = (lo == SENT);
          bool ok = (lo == k + 1u) || sent;
          if (__all(ok)) break;
          __builtin_amdgcn_s_sleep(1);
        }
        done = __any(sent);
      }
      if (done) break;
      {
        float z2 = __uint_as_float((unsigned)(tv >> 32));
        z2L[rowbase + ar] = z2;
        sz2L[rowbase + ar] = sqrtf(z2);
      }
      // ---- A-frags (coherent) + MFMA ----
      f32x4 af0, af1, af2, af3;
      {
        const unsigned rb = (unsigned)((rowbase + ar) * 256 + kg * 16);
        ld4w((const float*)(ws + OFF_ZBUFB), rb, rb + 64u, rb + 128u, rb + 192u,
             af0, af1, af2, af3);
      }
      bf16x8 afr[4];
      afr[0] = *(bf16x8*)&af0; afr[1] = *(bf16x8*)&af1;
      afr[2] = *(bf16x8*)&af2; afr[3] = *(bf16x8*)&af3;
      f32x4 dc[4];
#pragma unroll
      for (int nt = 0; nt < 4; ++nt) dc[nt] = (f32x4){0.f, 0.f, 0.f, 0.f};
#pragma unroll
      for (int kc = 0; kc < 4; ++kc) {
#pragma unroll
        for (int nt = 0; nt < 4; ++nt) {
          bf16x8 b = *(const bf16x8*)(vqeB + (((size_t)(s * 64 + nt * 16 + ar)) << 7)
                                      + kc * 32 + kg * 8);
          dc[nt] = __builtin_amdgcn_mfma_f32_16x16x32_bf16(afr[kc], b, dc[nt], 0, 0, 0);
        }
      }
      // ---- epilogue: certified bound, per-row L = min(a+e), candidate append ----
      float aV[4][4], eV[4][4], Lmin[4];
#pragma unroll
      for (int rr = 0; rr < 4; ++rr) Lmin[rr] = 1e30f;
#pragma unroll
      for (int nt = 0; nt < 4; ++nt) {
        const int code = s * 64 + nt * 16 + ar;
        const float es = esqG[code];
        const float se = sqrtf(es);
#pragma unroll
        for (int rr = 0; rr < 4; ++rr) {
          const int row = rowbase + kg * 4 + rr;
          float av = (z2L[row] - 2.0f * dc[nt][rr]) + es;
          float ev = fmaf(0.0082f * sz2L[row], se, 1e-3f);
          aV[nt][rr] = av; eV[nt][rr] = ev;
          float ae = av + ev;
          if (ae < Lmin[rr]) Lmin[rr] = ae;
        }
      }
#pragma unroll
      for (int m2 = 1; m2 < 16; m2 <<= 1)
#pragma unroll
        for (int rr = 0; rr < 4; ++rr) {
          float o = __shfl_xor(Lmin[rr], m2);
          if (o < Lmin[rr]) Lmin[rr] = o;
        }
#pragma unroll
      for (int nt = 0; nt < 4; ++nt)
#pragma unroll
        for (int rr = 0; rr < 4; ++rr)
          if (aV[nt][rr] - eV[nt][rr] <= Lmin[rr]) {
            const unsigned row = (unsigned)(rowbase + kg * 4 + rr);
            const unsigned code = (unsigned)(s * 64 + nt * 16 + ar);
            unsigned pos = atomicAdd(&candCount, 1u);
            candL[pos] = (row << 16) | code;
          }
      __syncthreads();
      // ---- exact f32 rescue: 4 lanes/entry, 128 entries per round trip ----
      const unsigned cnt = candCount;
      for (unsigned base = 0; base < cnt; base += 128u) {
        const unsigned eI = base + (unsigned)(tid >> 2);
        const int sub = tid & 3;
        const bool valid = eI < cnt;
        float dsum = 0.f;
        int row = 0, code = 0;
        if (valid) {
          unsigned en = candL[eI];
          row = (int)(en >> 16); code = (int)(en & 0xFFFFu);
          f32x4 zv0, zv1, zv2, zv3, zv4, zv5, zv6, zv7;
          const unsigned zb = (unsigned)(row * 512 + sub * 128);
          ld8w(zbuf, zb, zb + 16u, zb + 32u, zb + 48u,
               zb + 64u, zb + 80u, zb + 96u, zb + 112u,
               zv0, zv1, zv2, zv3, zv4, zv5, zv6, zv7);
          const float4* ep = (const float4*)(vqe + ((size_t)code << 7) + sub * 32);
          float4 e0 = ep[0], e1 = ep[1], e2 = ep[2], e3 = ep[3];
          float4 e4 = ep[4], e5 = ep[5], e6 = ep[6], e7 = ep[7];
          dsum = fmaf(zv0[0], e0.x, fmaf(zv0[1], e0.y, fmaf(zv0[2], e0.z, fmaf(zv0[3], e0.w, 0.f))));
          dsum = fmaf(zv1[0], e1.x, fmaf(zv1[1], e1.y, fmaf(zv1[2], e1.z, fmaf(zv1[3], e1.w, dsum))));
          dsum = fmaf(zv2[0], e2.x, fmaf(zv2[1], e2.y, fmaf(zv2[2], e2.z, fmaf(zv2[3], e2.w, dsum))));
          dsum = fmaf(zv3[0], e3.x, fmaf(zv3[1], e3.y, fmaf(zv3[2], e3.z, fmaf(zv3[3], e3.w, dsum))));
          dsum = fmaf(zv4[0], e4.x, fmaf(zv4[1], e4.y, fmaf(zv4[2], e4.z, fmaf(zv4[3], e4.w, dsum))));
          dsum = fmaf(zv5[0], e5.x, fmaf(zv5[1], e5.y, fmaf(zv5[2], e5.z, fmaf(zv5[3], e5.w, dsum))));
          dsum = fmaf(zv6[0], e6.x, fmaf(zv6[1], e6.y, fmaf(zv6[2], e6.z, fmaf(zv6[3], e6.w, dsum))));
          dsum = fmaf(zv7[0], e7.x, fmaf(zv7[1], e7.y, fmaf(zv7[2], e7.z, fmaf(zv7[3], e7.w, dsum))));
        }
        dsum += __shfl_xor(dsum, 1);
        dsum += __shfl_xor(dsum, 2);
        if (valid && sub == 0) {
          float d2 = (z2L[row] - 2.0f * dsum) + esqG[code];
          atomicMin(&rowminU[row], packkey(d2, (unsigned)code));
        }
      }
      __syncthreads();
      if (tid < 128) {
        u64 kk = rowminU[tid];
        rowminU[tid] = ~0ull;                 // reset before store (gated: next appends ≥2 hops away)
        if (tid == 0) candCount = 0u;
        st_coh64(&keys[(size_t)s * 128 + tid], kk | ((u64)(k + 1u) << 13));
      }
      k++;
    }
    return;
  }

  // ================= owner: blocks 0..127, row = blk =================
  float lnG = 0.0f, lnB = 0.0f, gtwv = 0.0f;
  if (tid < 64) { lnG = nrg[tid]; lnB = nrb[tid]; }
  else if (tid < 128) { lnG = nig[tid - 64]; lnB = nib[tid - 64]; }
  if (tid < 128) gtwv = gtw[tid];
  for (int i = tid; i < 32 * 65; i += NTHR) { memLr[i] = 0.0f; memLi[i] = 0.0f; }
  if (tid < 4) { totL[tid] = 0.0f; accL[tid] = 0.0f; }
  if (tid < 2) actM[tid] = ~0ull;
  for (int i = tid; i < 384; i += NTHR) arbWL[i] = aW[i];
  {
    int tok = x_seq[blk * TT];
    if (tid < 128) gwrowL[tid] = onema * enc[((size_t)tok << 7) + tid];
  }
  __syncthreads();
  if (tid < 64) pangL[tid] = atan2f(gwrowL[64 + tid], gwrowL[tid]);
  if (tid < 128) {
    float val = gwrowL[tid];
    float mu = wredsum(val) * 0.015625f;
    float xc = val - mu;
    float vr = wredsum(xc * xc) * 0.015625f;
    float z = xc * (1.0f / sqrtf(vr + 1e-5f)) * lnG + lnB;
    zfmL[tid] = z;
    st_coh_f32(&zbuf[(blk << 7) + tid], z);
    float zo = __shfl_xor(z, 1);
    if ((tid & 1) == 0) {
      unsigned pk = (unsigned)f2bf(z) | ((unsigned)f2bf(zo) << 16);
      st_coh32(&zbufB32[blk * 64 + (tid >> 1)], pk);
    }
    float s2 = wredsum(z * z);
    if (ln == 0) z2pL[wv] = s2;
  }
  drain_vm();
  __syncthreads();
  if (tid == 0) {
    float z2 = z2pL[0] + z2pL[1];
    st_coh64(&zdone64[blk * 2], (u64)1u | ((u64)__float_as_uint(z2) << 32));
  }

  int t = 0, it = 0;
  unsigned k = 0;
  for (;;) {
    const unsigned tag = k + 1u;
    float encN = 0.0f;
    {
      int tnext = (t + 1 < TT) ? t + 1 : t;
      if (tid < 128) {
        int tk = x_seq[blk * TT + tnext];
        encN = enc[((size_t)tk << 7) + tid];
      }
    }
    // ---------- C-prep on zfmL (overlaps server work) ----------
    if (tid < 192) {
      const int h = tid >> 6, j = tid & 63;
      const float* wr = qWr + h * 4096 + j * 64;
      const float* wi = qWi + h * 4096 + j * 64;
      float da = 0.0f, db_ = 0.0f, dc2 = 0.0f, de = 0.0f;
#pragma unroll 4
      for (int d4 = 0; d4 < 64; d4 += 4) {
        float4 wrv = *(const float4*)&wr[d4];
        float4 wiv = *(const float4*)&wi[d4];
        float4 crv = *(const float4*)&zfmL[d4];
        float4 civ = *(const float4*)&zfmL[64 + d4];
        da = fmaf(crv.x, wrv.x, fmaf(crv.y, wrv.y, fmaf(crv.z, wrv.z, fmaf(crv.w, wrv.w, da))));
        db_ = fmaf(civ.x, wiv.x, fmaf(civ.y, wiv.y, fmaf(civ.z, wiv.z, fmaf(civ.w, wiv.w, db_))));
        dc2 = fmaf(civ.x, wrv.x, fmaf(civ.y, wrv.y, fmaf(civ.z, wrv.z, fmaf(civ.w, wrv.w, dc2))));
        de = fmaf(crv.x, wiv.x, fmaf(crv.y, wiv.y, fmaf(crv.z, wiv.z, fmaf(crv.w, wiv.w, de))));
      }
      float brv = qbr[h * 64 + j], biv = qbi[h * 64 + j];
      qkL[2 * h][j] = da + brv - db_ - biv;
      qkL[2 * h + 1][j] = dc2 + brv + de + biv;
    } else if (tid < 224) {
      const int s2 = tid - 192;
      float a2 = 0.0f;
      for (int d = 0; d < 64; ++d)
        a2 = fmaf(memLr[s2 * 65 + d], zfmL[d], fmaf(memLi[s2 * 65 + d], zfmL[64 + d], a2));
      simL[s2] = a2;
    } else if (tid < 227) {
      const int h = tid - 224;
      float a2 = ab[h];
      for (int k2 = 0; k2 < 128; ++k2) a2 = fmaf(zfmL[k2], arbWL[h * 128 + k2], a2);
      scalL[3 + h] = a2;
    }
    __syncthreads();
    if (tid < 64) {
      float p = fmaf(qkL[0][tid], qkL[2][tid], qkL[1][tid] * qkL[3][tid]);
      p = wredsum(p);
      if (tid == 0) scalL[0] = 1.0f / (1.0f + expf(-p));
    } else if (tid < 96) {
      const int s2 = tid - 64;
      float v = simL[s2];
      float m = v;
#pragma unroll
      for (int msk = 16; msk > 0; msk >>= 1) m = fmaxf(m, __shfl_xor(m, msk));
      float e = expf(v - m);
      float ss = e;
#pragma unroll
      for (int msk = 16; msk > 0; msk >>= 1) ss += __shfl_xor(ss, msk);
      attnL[s2] = e / ss;
    } else if (tid == 96) {
      float a0 = scalL[3], a1 = scalL[4], a2 = scalL[5];
      float m = fmaxf(a0, fmaxf(a1, a2));
      float e0 = expf(a0 - m), e1 = expf(a1 - m), e2 = expf(a2 - m);
      float ssum = e0 + e1 + e2;
      scalL[3] = e0 / ssum; scalL[4] = e1 / ssum; scalL[5] = e2 / ssum;
    }
    __syncthreads();
    if (tid < 128) {
      const int d = ln;
      const float* ml = (wv == 0) ? memLr : memLi;
      float a2 = 0.0f;
#pragma unroll 4
      for (int s2 = 0; s2 < 32; ++s2) a2 = fmaf(attnL[s2], ml[s2 * 65 + d], a2);
      if (wv == 0) mrL[d] = a2; else miL[d] = a2;
    }
    // ---------- keys poll: per-wave, sync-free rounds ----------
    if (tid < 128) {
      const u64* kp = &keys[(size_t)tid * 128 + blk];
      u64 v;
      while (true) {
        v = ld_coh64(kp);
        if (__all(((unsigned)(v >> 13) & 0x7FFFFu) == tag)) break;
        __builtin_amdgcn_s_sleep(1);
      }
      kred[tid] = v;
    }
    __syncthreads();
    if (tid < 64) {
      u64 a = kred[tid], b = kred[tid + 64];
      if (b < a) a = b;
#pragma unroll
      for (int m2 = 32; m2 > 0; m2 >>= 1) { u64 o = shflx64(a, m2); if (o < a) a = o; }
      if (tid == 0) st_coh64(&finalA[blk * 2], a);
    }
    // ---------- finals poll: per-wave, sync-free rounds ----------
    if (tid < 128) {
      const u64* fp = &finalA[(size_t)tid * 2];
      u64 v;
      while (true) {
        v = ld_coh64(fp);
        if (__all(((unsigned)(v >> 13) & 0x7FFFFu) == tag)) break;
        __builtin_amdgcn_s_sleep(1);
      }
      key128L[tid] = v;
    }
    __syncthreads();
    // ---------- consensus (waves 0-1) || zq fetch + vq_loss (waves 2-3 ONLY) ----------
    const bool aoldb = ((actM[blk >> 6] >> (blk & 63)) & 1ull) != 0ull;
    if (tid < 128) {
      u64 key = key128L[tid];
      idxL[tid] = (unsigned)key & IDXM;
      float d2 = unpackd2(key);
      bool act_b = ((actM[tid >> 6] >> (tid & 63)) & 1ull) != 0ull;
      bool stop = (1.25f * 0.0078125f * d2) < hbias;
      u64 ball = __ballot(act_b && !stop);
      if (ln == 0) actN[tid >> 6] = ball;
    } else if (tid < 256) {              // FIX r12: bound the branch (was unbounded else -> LDS OOB)
      const int d = tid - 128;
      unsigned ii2 = (unsigned)key128L[blk] & IDXM;
      float zq = vqe[((size_t)ii2 << 7) + d];
      zqL[d] = zq;
      float df = zq - zfmL[d];
      float sm = wredsum(df * df);
      if (ln == 0) vqpL[wv - 2] = sm;
    }
    __syncthreads();
    const bool anyAct = (actN[0] | actN[1]) != 0ull;
    const bool mf = aoldb;
    if (tid < 2) actM[tid] = actN[tid];
    // ---------- candidate (no atan2 here; stash cand in mrL/miL) ----------
    if (tid < 64) {
      const int d = tid;
      float gate = scalL[0], g0 = scalL[3], g1 = scalL[4], g2 = scalL[5];
      float cr = zfmL[d], ci = zfmL[64 + d];
      float ur = fmaf(g0, qkL[4][d] * gate, fmaf(g1, mrL[d], g2 * zqL[d]));
      float ui = fmaf(g0, qkL[5][d] * gate, fmaf(g1, miL[d], g2 * zqL[64 + d]));
      float cdr = fmaf(0.4f, ur, 0.6f * cr);
      float cdi = fmaf(0.4f, ui, 0.6f * ci);
      mrL[d] = cdr; miL[d] = cdi;
      if (mf) { gwrowL[d] = cdr; gwrowL[64 + d] = cdi; }
    }
    __syncthreads();
    const bool newT = !(anyAct && it < MAXREC - 1);
    const bool finished = newT && (t == TT - 1);
    if (newT && !finished) {
      float pr = 0.0f;
      if (tid < 128) {
        pr = gwrowL[tid];
        outhB[((size_t)blk * TT + t) * 128 + tid] = f2bf(pr);
        float part = wredsum(pr * gtwv);
        if (ln == 0) wsumL[wv] = part;
      }
      __syncthreads();
      if (tid < 128) {
        float wg = 1.0f / (1.0f + expf(-(wsumL[0] + wsumL[1] + gtb0)));
        int slot = 31 - t;
        float* m = (tid < 64) ? &memLr[slot * 65 + tid] : &memLi[slot * 65 + (tid - 64)];
        *m = fmaf(wg, pr, (1.0f - wg) * (*m));
        gwrowL[tid] = fmaf(alpha, pr, onema * encN);
      }
      __syncthreads();
    }
    // ---------- LN + publish z(k+1): critical path ends here ----------
    if (!finished) {
      if (tid < 128) {
        float val = gwrowL[tid];
        float mu = wredsum(val) * 0.015625f;
        float xc = val - mu;
        float vr = wredsum(xc * xc) * 0.015625f;
        float z = xc * (1.0f / sqrtf(vr + 1e-5f)) * lnG + lnB;
        zfmL[tid] = z;
        st_coh_f32(&zbuf[(blk << 7) + tid], z);
        float zo = __shfl_xor(z, 1);
        if ((tid & 1) == 0) {
          unsigned pk = (unsigned)f2bf(z) | ((unsigned)f2bf(zo) << 16);
          st_coh32(&zbufB32[blk * 64 + (tid >> 1)], pk);
        }
        float s2 = wredsum(z * z);
        if (ln == 0) z2pL[wv] = s2;
      }
      drain_vm();
      __syncthreads();
      if (tid == 0) {
        float z2 = z2pL[0] + z2pL[1];
        st_coh64(&zdone64[blk * 2], (u64)(k + 2u) | ((u64)__float_as_uint(z2) << 32));
      }
    } else {
      __syncthreads();
    }
    // ---------- shadow: phase-diff (wave 0) || entropy (waves 2-3) ----------
    if (tid < 64) {
      const int d = tid;
      float cdr = mrL[d], cdi = miL[d];
      float ang = atan2f(cdi, cdr);
      float df = fabsf(ang - pangL[d]);
      df = fminf(df, TWO_PI_F - df);
      pangL[d] = ang;
      float dm = wredsum(df) * 0.015625f;
      if (d == 0) dmeanS = dm;
    } else if (tid >= 128 && tid < 256) {
      const int r = tid - 128;
      unsigned my = idxL[r];
      int c = 0;
#pragma unroll
      for (int j4 = 0; j4 < 32; ++j4) {
        uint4 q = *(const uint4*)&idxL[j4 * 4];
        c += (q.x == my) + (q.y == my) + (q.z == my) + (q.w == my);
      }
      float term = -0.0078125f * logf((float)c * 0.0078125f + 1e-10f);
      term = wredsum(term);
      if (ln == 0) entpL[wv - 2] = term;
    }
    __syncthreads();
    if (tid == 0) {
      float aold = mf ? 1.0f : 0.0f;
      float vql = 1.25f * (vqpL[0] + vqpL[1]) * 0.0078125f;
      accL[3] += aold * dmeanS;
      accL[2] += aold * 0.01f;
      if (mf) {
        accL[0] = vql;
        accL[1] = entpL[0] + entpL[1];
        dout[(size_t)LOGN + 4 + (size_t)blk * TT + t] = (float)idxL[blk];
      }
    }
    if (newT && !finished) {
      if (tid < 64) pangL[tid] = atan2f(gwrowL[64 + tid], gwrowL[tid]);
      if (tid < 4) { totL[tid] += accL[tid]; accL[tid] = 0.0f; }   // wave0 in-order after tid0 block
      if (tid < 2) actM[tid] = ~0ull;
    }
    __syncthreads();
    if (finished) break;
    if (newT) { t++; it = 0; } else { it++; }
    k++;
  }

  // epilogue
  if (tid < 128) outhB[((size_t)blk * TT + (TT - 1)) * 128 + tid] = f2bf(gwrowL[tid]);
  if (tid < 4) rst[blk * 4 + tid] = totL[tid] + accL[tid];
  __syncthreads();
  if (tid == 0) st_coh64(&zdone64[blk * 2], (u64)SENT);
}

// ================= MFMA decoder: 4096x8192x128 bf16 -> f32 =================
__global__ __launch_bounds__(256) void k_dec(
    const float* __restrict__ dbv, float* __restrict__ dout,
    const char* __restrict__ ws)
{
  const unsigned short* outhB = (const unsigned short*)(ws + OFF_OUTHB);
  const unsigned short* dWb = (const unsigned short*)(ws + OFF_WB);
  const float* rst = (const float*)(ws + OFF_RST);
  const int tid = threadIdx.x;
  if (blockIdx.x == 0 && tid < 4) {
    float s = 0.0f;
    for (int r = 0; r < 128; ++r) s += rst[r * 4 + tid];
    dout[(size_t)LOGN + tid] = s * (1.0f / 4096.0f);
  }
  const int w = tid >> 6, l = tid & 63;
  const int bm = blockIdx.x & 63;
  const int bn = blockIdx.x >> 6;
  const int ar = l & 15, kg = l >> 4;
  const int m_base = bm * 64;
  const int n_base = bn * 256 + w * 64;
  f32x4 acc[4][4];
#pragma unroll
  for (int mt = 0; mt < 4; ++mt)
#pragma unroll
    for (int nt = 0; nt < 4; ++nt) acc[mt][nt] = (f32x4){0.f, 0.f, 0.f, 0.f};
#pragma unroll
  for (int kc = 0; kc < 4; ++kc) {
    const int ko = kc * 32 + kg * 8;
    bf16x8 a[4], b[4];
#pragma unroll
    for (int mt = 0; mt < 4; ++mt)
      a[mt] = *(const bf16x8*)(outhB + (size_t)(m_base + mt * 16 + ar) * 128 + ko);
#pragma unroll
    for (int nt = 0; nt < 4; ++nt)
      b[nt] = *(const bf16x8*)(dWb + (size_t)(n_base + nt * 16 + ar) * 128 + ko);
#pragma unroll
    for (int mt = 0; mt < 4; ++mt)
#pragma unroll
      for (int nt = 0; nt < 4; ++nt)
        acc[mt][nt] = __builtin_amdgcn_mfma_f32_16x16x32_bf16(a[mt], b[nt], acc[mt][nt], 0, 0, 0);
  }
#pragma unroll
  for (int nt = 0; nt < 4; ++nt) {
    const int n = n_base + nt * 16 + ar;
    const float bv = dbv[n];
#pragma unroll
    for (int mt = 0; mt < 4; ++mt) {
#pragma unroll
      for (int rr = 0; rr < 4; ++rr) {
        const int m = m_base + mt * 16 + kg * 4 + rr;
        dout[(size_t)m * 8192 + n] = acc[mt][nt][rr] + bv;
      }
    }
  }
}

extern "C" void kernel_launch(void* const* d_in, const int* in_sizes, int n_in,
                              void* d_out, int out_size, void* d_ws, size_t ws_size,
                              hipStream_t stream) {
  (void)in_sizes; (void)n_in; (void)out_size; (void)ws_size;
  const int*   x_seq = (const int*)d_in[0];
  const float* enc = (const float*)d_in[1];
  const float* vq  = (const float*)d_in[2];
  const float* nrg = (const float*)d_in[3];
  const float* nrb = (const float*)d_in[4];
  const float* nig = (const float*)d_in[5];
  const float* nib = (const float*)d_in[6];
  const float* qWr = (const float*)d_in[7];
  const float* qbr = (const float*)d_in[8];
  const float* qWi = (const float*)d_in[9];
  const float* qbi = (const float*)d_in[10];
  const float* gtw = (const float*)d_in[11];
  const float* gtb = (const float*)d_in[12];
  const float* aW  = (const float*)d_in[13];
  const float* ab  = (const float*)d_in[14];
  const float* dW  = (const float*)d_in[15];
  const float* db  = (const float*)d_in[16];
  const float* hb  = (const float*)d_in[17];
  const float* ig  = (const float*)d_in[18];
  char* ws = (char*)d_ws;
  float* out = (float*)d_out;
  hipLaunchKernelGGL(sacrsn_init, dim3(1), dim3(512), 0, stream, ws);
  hipLaunchKernelGGL(k_prepv, dim3(1024), dim3(256), 0, stream, vq, ws);
  hipLaunchKernelGGL(sacrsn_main, dim3(NBLK), dim3(NTHR), 0, stream,
                     x_seq, enc, vq, nrg, nrb, nig, nib, qWr, qbr, qWi, qbi,
                     gtw, gtb, aW, ab, hb, ig, out, ws);
  hipLaunchKernelGGL(k_prepd, dim3(1024), dim3(256), 0, stream, dW, ws);
  hipLaunchKernelGGL(k_dec, dim3(2048), dim3(256), 0, stream, db, out, ws);
}

// Round 14
// 678.121 us; speedup vs baseline: 1.0638x; 1.0638x over previous
//
#include <hip/hip_runtime.h>
#include <math.h>

#define TT 32
#define MAXREC 8
#define NBLK 256
#define NTHR 512

// workspace byte offsets
#define OFF_ZBUF   0u          // 128*128 f32 = 65536 (exact z rows)
#define OFF_ZBUFB  65536u      // 128*128 bf16 = 32768 (z rows for MFMA)
#define OFF_KEYS   98304u      // 128 servers * 128 rows * 8B (tag-embedded)
#define OFF_ZDONE  229376u     // 128 * 16B: lo u64 {lo32=tag, hi32=z2}, hi u64 = finals overlay
#define OFF_ESQ    231424u     // 8192 f32 exact |e|^2
#define OFF_RST    264192u     // 128*4 f32
#define OFF_OUTHB  266240u     // 4096*128 bf16 = 1048576
#define OFF_WB     1314816u    // 2 MB: vqeB (main) then dWb (k_dec)

#define SENT 0x7FFFFFFFu
#define IDXM 0x1FFFu
#define LOGN 33554432u        // 128*32*8192
#define TWO_PI_F 6.283185307179586f

typedef float f32x4 __attribute__((ext_vector_type(4)));
typedef short bf16x8 __attribute__((ext_vector_type(8)));
typedef unsigned long long u64;

__device__ __forceinline__ float wredsum(float v) {
#pragma unroll
  for (int m = 32; m > 0; m >>= 1) v += __shfl_xor(v, m);
  return v;
}
__device__ __forceinline__ u64 shflx64(u64 v, int m) {
  int lo = __shfl_xor((int)(unsigned)(v & 0xffffffffull), m);
  int hi = __shfl_xor((int)(unsigned)(v >> 32), m);
  return ((u64)(unsigned)hi << 32) | (unsigned)lo;
}
// monotone float->u32 + 13-bit idx: u64-min == (min dist, then min idx)
__device__ __forceinline__ u64 packkey(float d, unsigned c) {
  unsigned u = __float_as_uint(d);
  u = (u & 0x80000000u) ? ~u : (u | 0x80000000u);
  return ((u64)u << 32) | c;
}
__device__ __forceinline__ float unpackd2(u64 key) {
  unsigned hi = (unsigned)(key >> 32);
  unsigned orig = (hi & 0x80000000u) ? (hi & 0x7fffffffu) : ~hi;
  return __uint_as_float(orig);
}
__device__ __forceinline__ unsigned short f2bf(float f) {
  unsigned u = __float_as_uint(f);
  unsigned r = (u >> 16) & 1u;
  u += 0x7fffu + r;
  return (unsigned short)(u >> 16);
}

// ---- coherent (cross-XCD, L2-bypass) accesses ----
__device__ __forceinline__ u64 ld_coh64(const u64* p) {
  u64 v;
  asm volatile("global_load_dwordx2 %0, %1, off sc0 sc1\n\ts_waitcnt vmcnt(0)"
               : "=&v"(v) : "v"(p) : "memory");
  return v;
}
__device__ __forceinline__ void st_coh_f32(float* p, float v) {
  asm volatile("global_store_dword %0, %1, off sc0 sc1" :: "v"(p), "v"(v) : "memory");
}
__device__ __forceinline__ void st_coh32(unsigned* p, unsigned v) {
  asm volatile("global_store_dword %0, %1, off sc0 sc1" :: "v"(p), "v"(v) : "memory");
}
__device__ __forceinline__ void st_coh64(u64* p, u64 v) {
  asm volatile("global_store_dwordx2 %0, %1, off sc0 sc1" :: "v"(p), "v"(v) : "memory");
}
__device__ __forceinline__ void drain_vm() {
  asm volatile("s_waitcnt vmcnt(0)" ::: "memory");
}
// 4 coherent 16B loads + wait (single round trip)
__device__ __forceinline__ void ld4w(const float* base,
    unsigned o0, unsigned o1, unsigned o2, unsigned o3,
    f32x4& a0, f32x4& a1, f32x4& a2, f32x4& a3) {
  asm volatile(
      "global_load_dwordx4 %0, %4, %8 sc0 sc1\n\t"
      "global_load_dwordx4 %1, %5, %8 sc0 sc1\n\t"
      "global_load_dwordx4 %2, %6, %8 sc0 sc1\n\t"
      "global_load_dwordx4 %3, %7, %8 sc0 sc1\n\t"
      "s_waitcnt vmcnt(0)"
      : "=&v"(a0), "=&v"(a1), "=&v"(a2), "=&v"(a3)
      : "v"(o0), "v"(o1), "v"(o2), "v"(o3), "s"(base)
      : "memory");
}
// 8 coherent 16B loads + single wait
__device__ __forceinline__ void ld8w(const float* base,
    unsigned o0, unsigned o1, unsigned o2, unsigned o3,
    unsigned o4, unsigned o5, unsigned o6, unsigned o7,
    f32x4& a0, f32x4& a1, f32x4& a2, f32x4& a3,
    f32x4& a4, f32x4& a5, f32x4& a6, f32x4& a7) {
  asm volatile(
      "global_load_dwordx4 %0, %8, %16 sc0 sc1\n\t"
      "global_load_dwordx4 %1, %9, %16 sc0 sc1\n\t"
      "global_load_dwordx4 %2, %10, %16 sc0 sc1\n\t"
      "global_load_dwordx4 %3, %11, %16 sc0 sc1\n\t"
      "global_load_dwordx4 %4, %12, %16 sc0 sc1\n\t"
      "global_load_dwordx4 %5, %13, %16 sc0 sc1\n\t"
      "global_load_dwordx4 %6, %14, %16 sc0 sc1\n\t"
      "global_load_dwordx4 %7, %15, %16 sc0 sc1\n\t"
      "s_waitcnt vmcnt(0)"
      : "=&v"(a0), "=&v"(a1), "=&v"(a2), "=&v"(a3),
        "=&v"(a4), "=&v"(a5), "=&v"(a6), "=&v"(a7)
      : "v"(o0), "v"(o1), "v"(o2), "v"(o3),
        "v"(o4), "v"(o5), "v"(o6), "v"(o7),
        "s"(base)
      : "memory");
}

__global__ __launch_bounds__(512) void sacrsn_init(char* __restrict__ ws) {
  // zero zdone+finals (block 0) and keys tags (all blocks) for cross-replay hygiene
  u64* zd = (u64*)(ws + OFF_ZDONE);
  u64* keys = (u64*)(ws + OFF_KEYS);
  const int g = blockIdx.x * 512 + threadIdx.x;
  if (blockIdx.x == 0 && threadIdx.x < 256) zd[threadIdx.x] = 0ull;
#pragma unroll
  for (int j = 0; j < 1; ++j) {
    int i = g;                      // 32 blocks * 512 = 16384 u64 = all keys
    if (i < 16384) keys[i] = 0ull;
  }
}

// vq_emb f32 -> bf16 (WB) + exact esq
__global__ __launch_bounds__(256) void k_prepv(const float* __restrict__ vqe,
                                               char* __restrict__ ws) {
  unsigned short* vqeB = (unsigned short*)(ws + OFF_WB);
  float* esqG = (float*)(ws + OFF_ESQ);
  const int i = (blockIdx.x * 256 + threadIdx.x) * 4;
  float4 v = *(const float4*)(vqe + i);
  ushort4 o;
  o.x = f2bf(v.x); o.y = f2bf(v.y); o.z = f2bf(v.z); o.w = f2bf(v.w);
  *(ushort4*)(vqeB + i) = o;
  if (blockIdx.x < 32) {
    const int c = blockIdx.x * 256 + threadIdx.x;
    const float4* e = (const float4*)(vqe + ((size_t)c << 7));
    float s = 0.f;
#pragma unroll 8
    for (int k4 = 0; k4 < 32; ++k4) {
      float4 q = e[k4];
      s = fmaf(q.x, q.x, fmaf(q.y, q.y, fmaf(q.z, q.z, fmaf(q.w, q.w, s))));
    }
    esqG[c] = s;
  }
}

// dec_W f32 -> bf16 (WB), runs AFTER main
__global__ __launch_bounds__(256) void k_prepd(const float* __restrict__ dW,
                                               char* __restrict__ ws) {
  unsigned short* dWb = (unsigned short*)(ws + OFF_WB);
  const int i = (blockIdx.x * 256 + threadIdx.x) * 4;
  float4 v = *(const float4*)(dW + i);
  ushort4 o;
  o.x = f2bf(v.x); o.y = f2bf(v.y); o.z = f2bf(v.z); o.w = f2bf(v.w);
  *(ushort4*)(dWb + i) = o;
}

__global__ __launch_bounds__(NTHR) void sacrsn_main(
    const int* __restrict__ x_seq, const float* __restrict__ enc,
    const float* __restrict__ vqe,
    const float* __restrict__ nrg, const float* __restrict__ nrb,
    const float* __restrict__ nig, const float* __restrict__ nib,
    const float* __restrict__ qWr, const float* __restrict__ qbr,
    const float* __restrict__ qWi, const float* __restrict__ qbi,
    const float* __restrict__ gtw, const float* __restrict__ gtb,
    const float* __restrict__ aW, const float* __restrict__ ab,
    const float* __restrict__ hbp, const float* __restrict__ igp,
    float* __restrict__ dout, char* __restrict__ ws)
{
  float* zbuf = (float*)(ws + OFF_ZBUF);
  unsigned* zbufB32 = (unsigned*)(ws + OFF_ZBUFB);
  u64*   keys = (u64*)(ws + OFF_KEYS);
  u64*   zdone64 = (u64*)(ws + OFF_ZDONE);       // slot r at [r*2]
  u64*   finalA = (u64*)(ws + OFF_ZDONE + 8u);   // slot r at [r*2] (upper half of 16B slot)
  const float* esqG = (const float*)(ws + OFF_ESQ);
  const unsigned short* vqeB = (const unsigned short*)(ws + OFF_WB);
  unsigned short* outhB = (unsigned short*)(ws + OFF_OUTHB);
  float* rst  = (float*)(ws + OFF_RST);

  const int tid = threadIdx.x;
  const int wv = tid >> 6, ln = tid & 63;
  const int blk = blockIdx.x;
  const bool owner = (blk < 128);

  // ---- LDS ----
  __shared__ float memLr[32 * 65];
  __shared__ float memLi[32 * 65];
  __shared__ float gwrowL[128], pangL[64], zfmL[128], zqL[128];
  __shared__ float qkL[6][64], simL[32], attnL[32], mrL[64], miL[64];
  __shared__ unsigned idxL[128] __attribute__((aligned(16)));
  __shared__ u64 key128L[128], kred[128];
  __shared__ float arbWL[3 * 128];
  __shared__ float scalL[8], entpL[2], vqpL[2], wsumL[2], z2pL[2];
  __shared__ float accL[4], totL[4];
  __shared__ float dmeanS;
  __shared__ unsigned iiS;
  __shared__ u64 actM[2], actN[2];
  // server-side
  __shared__ float z2L[128], sz2L[128];
  __shared__ u64 rowminU[128];
  __shared__ unsigned candL[8192];
  __shared__ unsigned candCount;

  const float alpha = 1.0f / (1.0f + expf(-igp[0]));
  const float onema = 1.0f - alpha;
  const float hbias = log1pf(expf(hbp[0]));
  const float gtb0 = gtb[0];

  if (!owner) {
    // ================= VQ server: 64 codes, MFMA + exact rescue =================
    const int s = blk - 128;
    const int w = tid >> 6, l = tid & 63;      // wave w owns rows w*16..w*16+15
    const int ar = l & 15, kg = l >> 4;
    const int rowbase = w * 16;
    if (tid < 128) rowminU[tid] = ~0ull;
    if (tid == 0) candCount = 0u;
    __syncthreads();
    unsigned k = 0;
    while (true) {
      // ---- per-wave poll: monotone (>= target) to tolerate skipped/dense tags ----
      u64 tv;
      bool done;
      {
        const u64* tp = &zdone64[(size_t)(rowbase + ar) * 2];
        bool sent;
        while (true) {
          tv = ld_coh64(tp);
          unsigned lo = (unsigned)tv;
          sent = (lo == SENT);
          bool ok = sent || ((int)(lo - (k + 1u)) >= 0);
          if (__all(ok)) break;
          __builtin_amdgcn_s_sleep(1);
        }
        done = __any(sent);
      }
      if (done) break;
      {
        float z2 = __uint_as_float((unsigned)(tv >> 32));
        z2L[rowbase + ar] = z2;
        sz2L[rowbase + ar] = sqrtf(z2);
      }
      // ---- A-frags (coherent) + MFMA ----
      f32x4 af0, af1, af2, af3;
      {
        const unsigned rb = (unsigned)((rowbase + ar) * 256 + kg * 16);
        ld4w((const float*)(ws + OFF_ZBUFB), rb, rb + 64u, rb + 128u, rb + 192u,
             af0, af1, af2, af3);
      }
      bf16x8 afr[4];
      afr[0] = *(bf16x8*)&af0; afr[1] = *(bf16x8*)&af1;
      afr[2] = *(bf16x8*)&af2; afr[3] = *(bf16x8*)&af3;
      f32x4 dc[4];
#pragma unroll
      for (int nt = 0; nt < 4; ++nt) dc[nt] = (f32x4){0.f, 0.f, 0.f, 0.f};
#pragma unroll
      for (int kc = 0; kc < 4; ++kc) {
#pragma unroll
        for (int nt = 0; nt < 4; ++nt) {
          bf16x8 b = *(const bf16x8*)(vqeB + (((size_t)(s * 64 + nt * 16 + ar)) << 7)
                                      + kc * 32 + kg * 8);
          dc[nt] = __builtin_amdgcn_mfma_f32_16x16x32_bf16(afr[kc], b, dc[nt], 0, 0, 0);
        }
      }
      // ---- certified bound, per-row L = min(a+e), candidates ----
      float aV[4][4], eV[4][4], Lmin[4];
#pragma unroll
      for (int rr = 0; rr < 4; ++rr) Lmin[rr] = 1e30f;
#pragma unroll
      for (int nt = 0; nt < 4; ++nt) {
        const int code = s * 64 + nt * 16 + ar;
        const float es = esqG[code];
        const float se = sqrtf(es);
#pragma unroll
        for (int rr = 0; rr < 4; ++rr) {
          const int row = rowbase + kg * 4 + rr;
          float av = (z2L[row] - 2.0f * dc[nt][rr]) + es;
          float ev = fmaf(0.0082f * sz2L[row], se, 1e-3f);
          aV[nt][rr] = av; eV[nt][rr] = ev;
          float ae = av + ev;
          if (ae < Lmin[rr]) Lmin[rr] = ae;
        }
      }
#pragma unroll
      for (int m2 = 1; m2 < 16; m2 <<= 1)
#pragma unroll
        for (int rr = 0; rr < 4; ++rr) {
          float o = __shfl_xor(Lmin[rr], m2);
          if (o < Lmin[rr]) Lmin[rr] = o;
        }
#pragma unroll
      for (int nt = 0; nt < 4; ++nt)
#pragma unroll
        for (int rr = 0; rr < 4; ++rr)
          if (aV[nt][rr] - eV[nt][rr] <= Lmin[rr]) {
            const unsigned row = (unsigned)(rowbase + kg * 4 + rr);
            const unsigned code = (unsigned)(s * 64 + nt * 16 + ar);
            unsigned pos = atomicAdd(&candCount, 1u);
            candL[pos] = (row << 16) | code;
          }
      __syncthreads();
      // ---- exact f32 rescue ----
      const unsigned cnt = candCount;
      for (unsigned base = 0; base < cnt; base += 128u) {
        const unsigned eI = base + (unsigned)(tid >> 2);
        const int sub = tid & 3;
        const bool valid = eI < cnt;
        float dsum = 0.f;
        int row = 0, code = 0;
        if (valid) {
          unsigned en = candL[eI];
          row = (int)(en >> 16); code = (int)(en & 0xFFFFu);
          f32x4 zv0, zv1, zv2, zv3, zv4, zv5, zv6, zv7;
          const unsigned zb = (unsigned)(row * 512 + sub * 128);
          ld8w(zbuf, zb, zb + 16u, zb + 32u, zb + 48u,
               zb + 64u, zb + 80u, zb + 96u, zb + 112u,
               zv0, zv1, zv2, zv3, zv4, zv5, zv6, zv7);
          const float4* ep = (const float4*)(vqe + ((size_t)code << 7) + sub * 32);
          float4 e0 = ep[0], e1 = ep[1], e2 = ep[2], e3 = ep[3];
          float4 e4 = ep[4], e5 = ep[5], e6 = ep[6], e7 = ep[7];
          dsum = fmaf(zv0[0], e0.x, fmaf(zv0[1], e0.y, fmaf(zv0[2], e0.z, fmaf(zv0[3], e0.w, 0.f))));
          dsum = fmaf(zv1[0], e1.x, fmaf(zv1[1], e1.y, fmaf(zv1[2], e1.z, fmaf(zv1[3], e1.w, dsum))));
          dsum = fmaf(zv2[0], e2.x, fmaf(zv2[1], e2.y, fmaf(zv2[2], e2.z, fmaf(zv2[3], e2.w, dsum))));
          dsum = fmaf(zv3[0], e3.x, fmaf(zv3[1], e3.y, fmaf(zv3[2], e3.z, fmaf(zv3[3], e3.w, dsum))));
          dsum = fmaf(zv4[0], e4.x, fmaf(zv4[1], e4.y, fmaf(zv4[2], e4.z, fmaf(zv4[3], e4.w, dsum))));
          dsum = fmaf(zv5[0], e5.x, fmaf(zv5[1], e5.y, fmaf(zv5[2], e5.z, fmaf(zv5[3], e5.w, dsum))));
          dsum = fmaf(zv6[0], e6.x, fmaf(zv6[1], e6.y, fmaf(zv6[2], e6.z, fmaf(zv6[3], e6.w, dsum))));
          dsum = fmaf(zv7[0], e7.x, fmaf(zv7[1], e7.y, fmaf(zv7[2], e7.z, fmaf(zv7[3], e7.w, dsum))));
        }
        dsum += __shfl_xor(dsum, 1);
        dsum += __shfl_xor(dsum, 2);
        if (valid && sub == 0) {
          float d2 = (z2L[row] - 2.0f * dsum) + esqG[code];
          atomicMin(&rowminU[row], packkey(d2, (unsigned)code));
        }
      }
      __syncthreads();
      if (tid < 128) {
        u64 kk = rowminU[tid];
        rowminU[tid] = ~0ull;
        if (tid == 0) candCount = 0u;
        st_coh64(&keys[(size_t)s * 128 + tid], kk | ((u64)(k + 1u) << 13));
      }
      k++;
    }
    return;
  }

  // ================= owner: blocks 0..127, row = blk =================
  float lnG = 0.0f, lnB = 0.0f, gtwv = 0.0f;
  if (tid < 64) { lnG = nrg[tid]; lnB = nrb[tid]; }
  else if (tid < 128) { lnG = nig[tid - 64]; lnB = nib[tid - 64]; }
  if (tid < 128) gtwv = gtw[tid];
  for (int i = tid; i < 32 * 65; i += NTHR) { memLr[i] = 0.0f; memLi[i] = 0.0f; }
  if (tid < 4) { totL[tid] = 0.0f; accL[tid] = 0.0f; }
  if (tid < 2) actM[tid] = ~0ull;
  for (int i = tid; i < 384; i += NTHR) arbWL[i] = aW[i];
  {
    int tok = x_seq[blk * TT];
    if (tid < 128) gwrowL[tid] = onema * enc[((size_t)tok << 7) + tid];
  }
  __syncthreads();
  if (tid < 64) pangL[tid] = atan2f(gwrowL[64 + tid], gwrowL[tid]);
  if (tid < 128) {
    float val = gwrowL[tid];
    float mu = wredsum(val) * 0.015625f;
    float xc = val - mu;
    float vr = wredsum(xc * xc) * 0.015625f;
    float z = xc * (1.0f / sqrtf(vr + 1e-5f)) * lnG + lnB;
    zfmL[tid] = z;
    st_coh_f32(&zbuf[(blk << 7) + tid], z);
    float zo = __shfl_xor(z, 1);
    if ((tid & 1) == 0) {
      unsigned pk = (unsigned)f2bf(z) | ((unsigned)f2bf(zo) << 16);
      st_coh32(&zbufB32[blk * 64 + (tid >> 1)], pk);
    }
    float s2 = wredsum(z * z);
    if (ln == 0) z2pL[wv] = s2;
  }
  drain_vm();
  __syncthreads();
  if (tid == 0) {
    float z2 = z2pL[0] + z2pL[1];
    st_coh64(&zdone64[blk * 2], (u64)1u | ((u64)__float_as_uint(z2) << 32));
  }

  int t = 0, it = 0;
  unsigned k = 1;     // tag of the z currently being served
  for (;;) {
    float encN = 0.0f;
    {
      int tnext = (t + 1 < TT) ? t + 1 : t;
      if (tid < 128) {
        int tk = x_seq[blk * TT + tnext];
        encN = enc[((size_t)tk << 7) + tid];
      }
    }
    // ---------- C-prep on zfmL(k) (overlaps server work) ----------
    if (tid < 192) {
      const int h = tid >> 6, j = tid & 63;
      const float* wr = qWr + h * 4096 + j * 64;
      const float* wi = qWi + h * 4096 + j * 64;
      float da = 0.0f, db_ = 0.0f, dc2 = 0.0f, de = 0.0f;
#pragma unroll 4
      for (int d4 = 0; d4 < 64; d4 += 4) {
        float4 wrv = *(const float4*)&wr[d4];
        float4 wiv = *(const float4*)&wi[d4];
        float4 crv = *(const float4*)&zfmL[d4];
        float4 civ = *(const float4*)&zfmL[64 + d4];
        da = fmaf(crv.x, wrv.x, fmaf(crv.y, wrv.y, fmaf(crv.z, wrv.z, fmaf(crv.w, wrv.w, da))));
        db_ = fmaf(civ.x, wiv.x, fmaf(civ.y, wiv.y, fmaf(civ.z, wiv.z, fmaf(civ.w, wiv.w, db_))));
        dc2 = fmaf(civ.x, wrv.x, fmaf(civ.y, wrv.y, fmaf(civ.z, wrv.z, fmaf(civ.w, wrv.w, dc2))));
        de = fmaf(crv.x, wiv.x, fmaf(crv.y, wiv.y, fmaf(crv.z, wiv.z, fmaf(crv.w, wiv.w, de))));
      }
      float brv = qbr[h * 64 + j], biv = qbi[h * 64 + j];
      qkL[2 * h][j] = da + brv - db_ - biv;
      qkL[2 * h + 1][j] = dc2 + brv + de + biv;
    } else if (tid < 224) {
      const int s2 = tid - 192;
      float a2 = 0.0f;
      for (int d = 0; d < 64; ++d)
        a2 = fmaf(memLr[s2 * 65 + d], zfmL[d], fmaf(memLi[s2 * 65 + d], zfmL[64 + d], a2));
      simL[s2] = a2;
    } else if (tid < 227) {
      const int h = tid - 224;
      float a2 = ab[h];
      for (int k2 = 0; k2 < 128; ++k2) a2 = fmaf(zfmL[k2], arbWL[h * 128 + k2], a2);
      scalL[3 + h] = a2;
    }
    __syncthreads();
    if (tid < 64) {
      float p = fmaf(qkL[0][tid], qkL[2][tid], qkL[1][tid] * qkL[3][tid]);
      p = wredsum(p);
      if (tid == 0) scalL[0] = 1.0f / (1.0f + expf(-p));
    } else if (tid < 96) {
      const int s2 = tid - 64;
      float v = simL[s2];
      float m = v;
#pragma unroll
      for (int msk = 16; msk > 0; msk >>= 1) m = fmaxf(m, __shfl_xor(m, msk));
      float e = expf(v - m);
      float ss = e;
#pragma unroll
      for (int msk = 16; msk > 0; msk >>= 1) ss += __shfl_xor(ss, msk);
      attnL[s2] = e / ss;
    } else if (tid == 96) {
      float a0 = scalL[3], a1 = scalL[4], a2 = scalL[5];
      float m = fmaxf(a0, fmaxf(a1, a2));
      float e0 = expf(a0 - m), e1 = expf(a1 - m), e2 = expf(a2 - m);
      float ssum = e0 + e1 + e2;
      scalL[3] = e0 / ssum; scalL[4] = e1 / ssum; scalL[5] = e2 / ssum;
    }
    __syncthreads();
    if (tid < 128) {
      const int d = ln;
      const float* ml = (wv == 0) ? memLr : memLi;
      float a2 = 0.0f;
#pragma unroll 4
      for (int s2 = 0; s2 < 32; ++s2) a2 = fmaf(attnL[s2], ml[s2 * 65 + d], a2);
      if (wv == 0) mrL[d] = a2; else miL[d] = a2;
    }
    // ---------- kred poll (echo == k) + own-row reduce ----------
    if (tid < 128) {
      const u64* kp = &keys[(size_t)tid * 128 + blk];
      u64 v;
      while (true) {
        v = ld_coh64(kp);
        if (__all(((unsigned)(v >> 13) & 0x7FFFFu) == k)) break;
        __builtin_amdgcn_s_sleep(1);
      }
      kred[tid] = v;
    }
    __syncthreads();
    if (tid < 64) {
      u64 a = kred[tid], b = kred[tid + 64];
      if (b < a) a = b;
#pragma unroll
      for (int m2 = 32; m2 > 0; m2 >>= 1) { u64 o = shflx64(a, m2); if (o < a) a = o; }
      if (tid == 0) { st_coh64(&finalA[blk * 2], a); iiS = (unsigned)a & IDXM; }
    }
    __syncthreads();
    const unsigned ii = iiS;
    const bool mf = ((actM[blk >> 6] >> (blk & 63)) & 1ull) != 0ull;
    // ---------- zq + vq partials (uses zfmL(k) before overwrite) ----------
    if (tid < 128) {
      float zq = vqe[((size_t)ii << 7) + tid];
      float df = zq - zfmL[tid];
      float sm = wredsum(df * df);
      if (ln == 0) vqpL[wv] = sm;
      zqL[tid] = zq;
    }
    __syncthreads();
    // ---------- cand + specOwn ----------
    if (tid < 64) {
      const int d = tid;
      float gate = scalL[0], g0 = scalL[3], g1 = scalL[4], g2 = scalL[5];
      float cr = zfmL[d], ci = zfmL[64 + d];
      float ur = fmaf(g0, qkL[4][d] * gate, fmaf(g1, mrL[d], g2 * zqL[d]));
      float ui = fmaf(g0, qkL[5][d] * gate, fmaf(g1, miL[d], g2 * zqL[64 + d]));
      float cdr = fmaf(0.4f, ur, 0.6f * cr);
      float cdi = fmaf(0.4f, ui, 0.6f * ci);
      mrL[d] = cdr; miL[d] = cdi;                 // for shadow phase-diff
      zqL[d]      = mf ? cdr : gwrowL[d];         // specOwn (pre-merge gw(k+1))
      zqL[64 + d] = mf ? cdi : gwrowL[64 + d];
    }
    __syncthreads();
    // ---------- SPECULATIVE publish z(tag k+1): critical path ends here ----------
    const bool specMerge = (t < TT - 1);
    if (tid < 128) {
      float g = specMerge ? fmaf(alpha, zqL[tid], onema * encN) : zqL[tid];
      float mu = wredsum(g) * 0.015625f;
      float xc = g - mu;
      float vr = wredsum(xc * xc) * 0.015625f;
      float z = xc * (1.0f / sqrtf(vr + 1e-5f)) * lnG + lnB;
      zfmL[tid] = z;
      st_coh_f32(&zbuf[(blk << 7) + tid], z);
      float zo = __shfl_xor(z, 1);
      if ((tid & 1) == 0) {
        unsigned pk = (unsigned)f2bf(z) | ((unsigned)f2bf(zo) << 16);
        st_coh32(&zbufB32[blk * 64 + (tid >> 1)], pk);
      }
      float s2 = wredsum(z * z);
      if (ln == 0) z2pL[wv] = s2;
    }
    drain_vm();
    __syncthreads();
    if (tid == 0) {
      float z2 = z2pL[0] + z2pL[1];
      st_coh64(&zdone64[blk * 2], (u64)(k + 1u) | ((u64)__float_as_uint(z2) << 32));
    }
    // ======== shadow (overlaps servers' next VQ) ========
    // finals poll (tag k)
    if (tid < 128) {
      const u64* fp = &finalA[(size_t)tid * 2];
      u64 v;
      while (true) {
        v = ld_coh64(fp);
        if (__all(((unsigned)(v >> 13) & 0x7FFFFu) == k)) break;
        __builtin_amdgcn_s_sleep(1);
      }
      key128L[tid] = v;
    }
    __syncthreads();
    if (tid < 128) {
      u64 key = key128L[tid];
      idxL[tid] = (unsigned)key & IDXM;
      float d2 = unpackd2(key);
      bool act_b = ((actM[tid >> 6] >> (tid & 63)) & 1ull) != 0ull;
      bool stop = (1.25f * 0.0078125f * d2) < hbias;
      u64 ball = __ballot(act_b && !stop);
      if (ln == 0) actN[tid >> 6] = ball;
    }
    __syncthreads();
    const bool anyAct = (actN[0] | actN[1]) != 0ull;
    const bool actualNewT = (!anyAct) || (it == MAXREC - 1);
    const bool mispredict = !actualNewT;
    const bool finished = actualNewT && (t == TT - 1);
    // phase-diff (wave 0) || entropy (waves 2-3)
    if (tid < 64) {
      const int d = tid;
      float ang = atan2f(miL[d], mrL[d]);
      float df = fabsf(ang - pangL[d]);
      df = fminf(df, TWO_PI_F - df);
      pangL[d] = ang;
      float dm = wredsum(df) * 0.015625f;
      if (d == 0) dmeanS = dm;
    } else if (tid >= 128 && tid < 256) {
      const int r = tid - 128;
      unsigned my = idxL[r];
      int c = 0;
#pragma unroll
      for (int j4 = 0; j4 < 32; ++j4) {
        uint4 q = *(const uint4*)&idxL[j4 * 4];
        c += (q.x == my) + (q.y == my) + (q.z == my) + (q.w == my);
      }
      float term = -0.0078125f * logf((float)c * 0.0078125f + 1e-10f);
      term = wredsum(term);
      if (ln == 0) entpL[wv - 2] = term;
    }
    __syncthreads();
    if (tid == 0) {
      float aold = mf ? 1.0f : 0.0f;
      accL[3] += aold * dmeanS;
      accL[2] += aold * 0.01f;
      if (mf) {
        accL[0] = 1.25f * (vqpL[0] + vqpL[1]) * 0.0078125f;
        accL[1] = entpL[0] + entpL[1];
        dout[(size_t)LOGN + 4 + (size_t)blk * TT + t] = (float)ii;
      }
    }
    if (tid < 2) actM[tid] = actN[tid];
    __syncthreads();
    if (mispredict) {
      // rollback: correct z = LN(specOwn), republish tag k+2 (all owners agree)
      if (tid < 128) gwrowL[tid] = zqL[tid];
      __syncthreads();
      if (tid < 128) {
        float g = gwrowL[tid];
        float mu = wredsum(g) * 0.015625f;
        float xc = g - mu;
        float vr = wredsum(xc * xc) * 0.015625f;
        float z = xc * (1.0f / sqrtf(vr + 1e-5f)) * lnG + lnB;
        zfmL[tid] = z;
        st_coh_f32(&zbuf[(blk << 7) + tid], z);
        float zo = __shfl_xor(z, 1);
        if ((tid & 1) == 0) {
          unsigned pk = (unsigned)f2bf(z) | ((unsigned)f2bf(zo) << 16);
          st_coh32(&zbufB32[blk * 64 + (tid >> 1)], pk);
        }
        float s2 = wredsum(z * z);
        if (ln == 0) z2pL[wv] = s2;
      }
      drain_vm();
      __syncthreads();
      if (tid == 0) {
        float z2 = z2pL[0] + z2pL[1];
        st_coh64(&zdone64[blk * 2], (u64)(k + 2u) | ((u64)__float_as_uint(z2) << 32));
      }
      __syncthreads();
      k += 2; it += 1;
      continue;
    }
    if (finished) break;
    // ---------- commit t-advance (speculation verified) ----------
    {
      float pr = 0.0f;
      if (tid < 128) {
        pr = zqL[tid];
        outhB[((size_t)blk * TT + t) * 128 + tid] = f2bf(pr);
        float part = wredsum(pr * gtwv);
        if (ln == 0) wsumL[wv] = part;
      }
      __syncthreads();
      if (tid < 128) {
        float wg = 1.0f / (1.0f + expf(-(wsumL[0] + wsumL[1] + gtb0)));
        int slot = 31 - t;
        float* m = (tid < 64) ? &memLr[slot * 65 + tid] : &memLi[slot * 65 + (tid - 64)];
        *m = fmaf(wg, pr, (1.0f - wg) * (*m));
        gwrowL[tid] = fmaf(alpha, pr, onema * encN);   // merged gw(t+1)
      }
      __syncthreads();
      if (tid < 64) pangL[tid] = atan2f(gwrowL[64 + tid], gwrowL[tid]);
      if (tid < 4) { totL[tid] += accL[tid]; accL[tid] = 0.0f; }
      if (tid < 2) actM[tid] = ~0ull;
      __syncthreads();
    }
    t++; it = 0; k += 1;
  }

  // epilogue (finished): final gw = specOwn (zqL)
  if (tid < 128) outhB[((size_t)blk * TT + (TT - 1)) * 128 + tid] = f2bf(zqL[tid]);
  if (tid < 4) rst[blk * 4 + tid] = totL[tid] + accL[tid];
  __syncthreads();
  if (tid == 0) st_coh64(&zdone64[blk * 2], (u64)SENT);
}

// ================= MFMA decoder: 4096x8192x128 bf16 -> f32 =================
__global__ __launch_bounds__(256) void k_dec(
    const float* __restrict__ dbv, float* __restrict__ dout,
    const char* __restrict__ ws)
{
  const unsigned short* outhB = (const unsigned short*)(ws + OFF_OUTHB);
  const unsigned short* dWb = (const unsigned short*)(ws + OFF_WB);
  const float* rst = (const float*)(ws + OFF_RST);
  const int tid = threadIdx.x;
  if (blockIdx.x == 0 && tid < 4) {
    float s = 0.0f;
    for (int r = 0; r < 128; ++r) s += rst[r * 4 + tid];
    dout[(size_t)LOGN + tid] = s * (1.0f / 4096.0f);
  }
  const int w = tid >> 6, l = tid & 63;
  const int bm = blockIdx.x & 63;
  const int bn = blockIdx.x >> 6;
  const int ar = l & 15, kg = l >> 4;
  const int m_base = bm * 64;
  const int n_base = bn * 256 + w * 64;
  f32x4 acc[4][4];
#pragma unroll
  for (int mt = 0; mt < 4; ++mt)
#pragma unroll
    for (int nt = 0; nt < 4; ++nt) acc[mt][nt] = (f32x4){0.f, 0.f, 0.f, 0.f};
#pragma unroll
  for (int kc = 0; kc < 4; ++kc) {
    const int ko = kc * 32 + kg * 8;
    bf16x8 a[4], b[4];
#pragma unroll
    for (int mt = 0; mt < 4; ++mt)
      a[mt] = *(const bf16x8*)(outhB + (size_t)(m_base + mt * 16 + ar) * 128 + ko);
#pragma unroll
    for (int nt = 0; nt < 4; ++nt)
      b[nt] = *(const bf16x8*)(dWb + (size_t)(n_base + nt * 16 + ar) * 128 + ko);
#pragma unroll
    for (int mt = 0; mt < 4; ++mt)
#pragma unroll
      for (int nt = 0; nt < 4; ++nt)
        acc[mt][nt] = __builtin_amdgcn_mfma_f32_16x16x32_bf16(a[mt], b[nt], acc[mt][nt], 0, 0, 0);
  }
#pragma unroll
  for (int nt = 0; nt < 4; ++nt) {
    const int n = n_base + nt * 16 + ar;
    const float bv = dbv[n];
#pragma unroll
    for (int mt = 0; mt < 4; ++mt) {
#pragma unroll
      for (int rr = 0; rr < 4; ++rr) {
        const int m = m_base + mt * 16 + kg * 4 + rr;
        dout[(size_t)m * 8192 + n] = acc[mt][nt][rr] + bv;
      }
    }
  }
}

extern "C" void kernel_launch(void* const* d_in, const int* in_sizes, int n_in,
                              void* d_out, int out_size, void* d_ws, size_t ws_size,
                              hipStream_t stream) {
  (void)in_sizes; (void)n_in; (void)out_size; (void)ws_size;
  const int*   x_seq = (const int*)d_in[0];
  const float* enc = (const float*)d_in[1];
  const float* vq  = (const float*)d_in[2];
  const float* nrg = (const float*)d_in[3];
  const float* nrb = (const float*)d_in[4];
  const float* nig = (const float*)d_in[5];
  const float* nib = (const float*)d_in[6];
  const float* qWr = (const float*)d_in[7];
  const float* qbr = (const float*)d_in[8];
  const float* qWi = (const float*)d_in[9];
  const float* qbi = (const float*)d_in[10];
  const float* gtw = (const float*)d_in[11];
  const float* gtb = (const float*)d_in[12];
  const float* aW  = (const float*)d_in[13];
  const float* ab  = (const float*)d_in[14];
  const float* dW  = (const float*)d_in[15];
  const float* db  = (const float*)d_in[16];
  const float* hb  = (const float*)d_in[17];
  const float* ig  = (const float*)d_in[18];
  char* ws = (char*)d_ws;
  float* out = (float*)d_out;
  hipLaunchKernelGGL(sacrsn_init, dim3(32), dim3(512), 0, stream, ws);
  hipLaunchKernelGGL(k_prepv, dim3(1024), dim3(256), 0, stream, vq, ws);
  hipLaunchKernelGGL(sacrsn_main, dim3(NBLK), dim3(NTHR), 0, stream,
                     x_seq, enc, vq, nrg, nrb, nig, nib, qWr, qbr, qWi, qbi,
                     gtw, gtb, aW, ab, hb, ig, out, ws);
  hipLaunchKernelGGL(k_prepd, dim3(1024), dim3(256), 0, stream, dW, ws);
  hipLaunchKernelGGL(k_dec, dim3(2048), dim3(256), 0, stream, db, out, ws);
}